// Round 9
// baseline (343.813 us; speedup 1.0000x reference)
//
#include <hip/hip_runtime.h>
#include <hip/hip_cooperative_groups.h>
#include <math.h>

namespace cg = cooperative_groups;

#define BB 64
#define HH 1024
#define VV 32000
#define SRC 128

typedef __attribute__((ext_vector_type(8))) __bf16 bf16x8;
typedef __attribute__((ext_vector_type(8))) unsigned short ushort8;
typedef __attribute__((ext_vector_type(4))) float f32x4;

__device__ __forceinline__ float sigmoidf_(float x){ return 1.f/(1.f+expf(-x)); }

__device__ __forceinline__ unsigned short f2bf(float f){
    union { float f; unsigned u; } v; v.f = f;
    unsigned r = v.u + 0x7FFFu + ((v.u >> 16) & 1u);   // round-to-nearest-even
    return (unsigned short)(r >> 16);
}

__device__ __forceinline__ void cvt8(const float4& x, const float4& y, unsigned short* dst){
    ushort8 s;
    s[0]=f2bf(x.x); s[1]=f2bf(x.y); s[2]=f2bf(x.z); s[3]=f2bf(x.w);
    s[4]=f2bf(y.x); s[5]=f2bf(y.y); s[6]=f2bf(y.z); s[7]=f2bf(y.w);
    *(ushort8*)dst = s;
}

// ---- 64x128 MFMA tile, 512 threads (8 waves, wave w owns 16 cols) ----
// A[64,*] from two sources split at k=1024 (optional row-gather via tk on A0);
// B row-major [N,K] split at global-k K0. One barrier per BK=64 tile,
// register-prefetch double-buffered LDS. acc[4] f32x4 out (rows fm*16+lr*4+r).
__device__ __forceinline__ void tile_mm(
    const int* tk, const float* A0, const float* A1,
    const float* B0, const float* B1, int K0, int ldb,
    int n0, int kbase, int nt,
    unsigned short* AsL, unsigned short* BsL, f32x4* acc)
{
    const int tid = threadIdx.x;
    const int am = tid >> 3, ak = (tid & 7) << 3;   // A: 64 rows x 8-float chunks
    const int bn = tid >> 2, bk = (tid & 3) << 4;   // B: 128 rows x 16-float chunks
    const int arow = tk ? tk[am] : am;
    float4 aR[2], bR[4];
    auto loadG = [&](int t){
        int ka = kbase + (t << 6) + ak;             // never straddles 1024
        const float* Ap = (ka < 1024) ? (A0 + (size_t)arow*HH + ka)
                                      : (A1 + (size_t)am*HH + (ka - 1024));
        aR[0] = *(const float4*)(Ap);
        aR[1] = *(const float4*)(Ap + 4);
        int kg = kbase + (t << 6);
        const float* Bp; int kb;
        if (kg < K0) { Bp = B0; kb = kg; } else { Bp = B1; kb = kg - K0; }
        const float* Bq = Bp + (size_t)(n0 + bn) * ldb + kb + bk;
        #pragma unroll
        for (int i = 0; i < 4; ++i) bR[i] = *(const float4*)(Bq + i*4);
    };
    auto writeL = [&](int buf){
        cvt8(aR[0], aR[1], &AsL[buf*4608 + am*72 + ak]);
        cvt8(bR[0], bR[1], &BsL[buf*9216 + bn*72 + bk]);
        cvt8(bR[2], bR[3], &BsL[buf*9216 + bn*72 + bk + 8]);
    };
    loadG(0); writeL(0);
    __syncthreads();
    const int lane = tid & 63, w = tid >> 6;
    const int lr = lane >> 4, lc = lane & 15;
    for (int t = 0; t < nt; ++t) {
        const int cur = t & 1;
        if (t + 1 < nt) loadG(t + 1);               // overlaps MFMA below
        #pragma unroll
        for (int ks = 0; ks < 2; ++ks) {
            bf16x8 bF = *(const bf16x8*)&BsL[cur*9216 + (w*16 + lc)*72 + ks*32 + lr*8];
            #pragma unroll
            for (int fm = 0; fm < 4; ++fm) {
                bf16x8 aF = *(const bf16x8*)&AsL[cur*4608 + (fm*16 + lc)*72 + ks*32 + lr*8];
                acc[fm] = __builtin_amdgcn_mfma_f32_16x16x32_bf16(aF, bF, acc[fm], 0, 0, 0);
            }
        }
        if (t + 1 < nt) { writeL((t + 1) & 1); __syncthreads(); }
    }
}

// ================== the whole decoder step as one cooperative kernel ==================
// Phases (grid.sync between): 0 L0-GEMM+u_e | 1 lstm0+scores | 2 L1-GEMM+smctx |
// 3 lstm1 | 4 concat-GEMM | 5 reduce+tanh | 6 out-GEMM+(m,s) | 7 lse-merge+subtract.
// Launched cooperatively with (0,7); fallback: 8 plain launches of (p,p).
__global__ __launch_bounds__(512)
void mega(const int* __restrict__ tokens, const float* __restrict__ h0,
          const float* __restrict__ c0, const float* __restrict__ enc,
          const float* __restrict__ emb,
          const float* __restrict__ W_ih, const float* __restrict__ W_hh,
          const float* __restrict__ b_ih, const float* __restrict__ b_hh,
          const float* __restrict__ attn_W, const float* __restrict__ attn_v,
          const float* __restrict__ concat_W, const float* __restrict__ concat_b,
          const float* __restrict__ out_W, const float* __restrict__ out_b,
          float* __restrict__ logp, float* __restrict__ h_n, float* __restrict__ c_n,
          float* __restrict__ gates, float* __restrict__ h1, float* __restrict__ h_top,
          float* __restrict__ ctx, float* __restrict__ h_c,
          float* __restrict__ u_e, float* __restrict__ scores,
          float2* __restrict__ ms, float* __restrict__ catP,
          int ph_lo, int ph_hi)
{
    __shared__ __align__(16) unsigned short AsS[2*4608];   // 18.4 KB (aliased by small phases)
    __shared__ __align__(16) unsigned short BsS[2*9216];   // 36.9 KB
    __shared__ float wm[8][64], wsum[8][64];               // 4 KB
    const int bid = blockIdx.x, tid = threadIdx.x;

    for (int ph = ph_lo; ph <= ph_hi; ++ph) {
        if (ph > ph_lo) cg::this_grid().sync();

        if (ph == 0 || ph == 2 || ph == 4) {
            // ---- split-K weight GEMMs (+ fused side units) ----
            const int* tk = nullptr;
            const float *A0, *A1, *B0, *B1; int K0, ldb, N, NG, NU; float* Cb;
            if (ph == 0) { tk = tokens; A0 = emb; A1 = h0;
                           B0 = W_ih; B1 = W_hh; K0 = 1024; ldb = 1024;
                           N = 4096; Cb = gates; NG = 256; NU = 272; }
            else if (ph == 2) { A0 = h1; A1 = h0 + BB*HH;
                           B0 = W_ih + (size_t)4096*1024; B1 = W_hh + (size_t)4096*1024;
                           K0 = 1024; ldb = 1024; N = 4096; Cb = gates; NG = 256; NU = 384; }
            else         { A0 = ctx; A1 = h_top; B0 = concat_W; B1 = concat_W;
                           K0 = 1 << 30; ldb = 2048; N = 1024; Cb = catP; NG = 64; NU = 64; }
            const int ntiles = N >> 7;
            for (int u = bid; u < NU; u += 256) {
                __syncthreads();                    // protect LDS reuse across units
                if (u < NG) {
                    f32x4 acc[4] = {};
                    int n0 = (u % ntiles) * 128;
                    int slice = u / ntiles;
                    tile_mm(tk, A0, A1, B0, B1, K0, ldb, n0, slice*256, 4, AsS, BsS, acc);
                    float* Cp = Cb + (size_t)slice * 64 * N;
                    const int lane = tid & 63, w = tid >> 6;
                    const int lr = lane >> 4, lc = lane & 15;
                    const int n = n0 + w*16 + lc;
                    #pragma unroll
                    for (int fm = 0; fm < 4; ++fm)
                        #pragma unroll
                        for (int r = 0; r < 4; ++r)
                            Cp[(size_t)(fm*16 + lr*4 + r)*N + n] = acc[fm][r];
                } else if (ph == 0) {
                    // u_e[k] = sum_h attn_v[h] * attn_W[h][1024+k] (score bias terms cancel)
                    int ue = u - 256;               // 0..15
                    float4 (*red4)[16] = (float4 (*)[16])AsS;
                    int kq = tid & 15, hp = tid >> 4;   // hp 0..31
                    int k = 1024 + ue*64 + kq*4;
                    float4 s4 = {0.f,0.f,0.f,0.f};
                    for (int h = hp; h < HH; h += 32) {
                        float vh = attn_v[h];
                        float4 wv = *(const float4*)&attn_W[(size_t)h*2048 + k];
                        s4.x = fmaf(vh, wv.x, s4.x); s4.y = fmaf(vh, wv.y, s4.y);
                        s4.z = fmaf(vh, wv.z, s4.z); s4.w = fmaf(vh, wv.w, s4.w);
                    }
                    red4[hp][kq] = s4;
                    __syncthreads();
                    if (tid < 16) {
                        float4 t4 = {0.f,0.f,0.f,0.f};
                        #pragma unroll
                        for (int i = 0; i < 32; ++i) {
                            float4 rv = red4[i][tid];
                            t4.x += rv.x; t4.y += rv.y; t4.z += rv.z; t4.w += rv.w;
                        }
                        *(float4*)&u_e[ue*64 + tid*4] = t4;
                    }
                } else {
                    // smctx: softmax over scores[b,:] + context (ph == 2)
                    int su = u - 256;               // 0..127
                    int b = su >> 1;
                    int h = ((su & 1) << 9) + tid;
                    float* wl = (float*)AsS;
                    if (tid < SRC) wl[tid] = scores[b*SRC + tid];
                    __syncthreads();
                    float m = -INFINITY;
                    #pragma unroll 8
                    for (int l = 0; l < SRC; ++l) m = fmaxf(m, wl[l]);
                    float sum = 0.f;
                    #pragma unroll 8
                    for (int l = 0; l < SRC; ++l) sum += expf(wl[l] - m);
                    float inv = 1.f / sum;
                    __syncthreads();
                    if (tid < SRC) wl[tid] = expf(wl[tid] - m) * inv;
                    __syncthreads();
                    float a = 0.f;
                    #pragma unroll 4
                    for (int l = 0; l < SRC; ++l)
                        a = fmaf(wl[l], enc[(size_t)(l*BB + b)*HH + h], a);
                    ctx[b*HH + h] = a;
                }
            }
        } else if (ph == 1 || ph == 3) {
            // ---- LSTM pointwise (8 split-K partial sum) [+ scores in ph 1] ----
            const int L = (ph == 1) ? 0 : 1;
            const float* bih = b_ih + L*4096;
            const float* bhh = b_hh + L*4096;
            const float* c0l = c0 + L*BB*HH;
            float* hn = h_n + L*BB*HH;
            float* cn = c_n + L*BB*HH;
            float* hout = (ph == 1) ? h1 : h_top;
            const int NU = (ph == 1) ? 1152 : 128;
            for (int u = bid; u < NU; u += 256) {
                if (u < 128) {
                    int idx = (u << 9) + tid;       // 0..65535
                    int b = idx >> 10, k = idx & 1023;
                    float ig = bih[k]        + bhh[k];
                    float fg = bih[1024 + k] + bhh[1024 + k];
                    float gg = bih[2048 + k] + bhh[2048 + k];
                    float og = bih[3072 + k] + bhh[3072 + k];
                    #pragma unroll
                    for (int s = 0; s < 8; ++s) {
                        const float* gs = gates + (size_t)s*BB*4096 + b*4096;
                        ig += gs[k]; fg += gs[1024 + k];
                        gg += gs[2048 + k]; og += gs[3072 + k];
                    }
                    float c = sigmoidf_(fg)*c0l[b*HH + k] + sigmoidf_(ig)*tanhf(gg);
                    float hh = sigmoidf_(og)*tanhf(c);
                    cn[b*HH + k] = c;
                    hn[b*HH + k] = hh;
                    hout[b*HH + k] = hh;
                } else {
                    // scores[b,l] = u_e . enc[l,b,:] — one (b,l) pair per wave
                    int p = ((u - 128) << 3) + (tid >> 6);  // 0..8191
                    int b = p >> 7, l = p & 127;
                    int lane = tid & 63;
                    const float* e = enc + (size_t)(l*BB + b)*HH;
                    float s = 0.f;
                    #pragma unroll
                    for (int t = 0; t < 16; ++t)
                        s = fmaf(u_e[lane + 64*t], e[lane + 64*t], s);
                    #pragma unroll
                    for (int o = 32; o > 0; o >>= 1) s += __shfl_xor(s, o);
                    if (lane == 0) scores[b*SRC + l] = s;
                }
            }
        } else if (ph == 5) {
            // ---- h_c = tanh(bias + sum of 8 concat partials) ----
            for (int u = bid; u < 128; u += 256) {
                int idx = (u << 9) + tid;
                int n = idx & 1023;
                float s = concat_b[n];
                #pragma unroll
                for (int si = 0; si < 8; ++si) s += catP[(size_t)si*65536 + idx];
                h_c[idx] = tanhf(s);
            }
        } else if (ph == 6) {
            // ---- out-projection + fused per-block row (max, expsum) ----
            for (int u = bid; u < 250; u += 256) {
                __syncthreads();
                f32x4 acc[4] = {};
                int n0 = u * 128;
                tile_mm(nullptr, h_c, h_c, out_W, out_W, 1 << 30, 1024,
                        n0, 0, 16, AsS, BsS, acc);
                const int lane = tid & 63, w = tid >> 6;
                const int lr = lane >> 4, lc = lane & 15;
                const int n = n0 + w*16 + lc;
                const float bv = out_b[n];
                #pragma unroll
                for (int fm = 0; fm < 4; ++fm) {
                    #pragma unroll
                    for (int r = 0; r < 4; ++r) {
                        float v = acc[fm][r] + bv;
                        logp[(size_t)(fm*16 + lr*4 + r)*VV + n] = v;
                        float mx = v;
                        #pragma unroll
                        for (int o = 1; o < 16; o <<= 1) mx = fmaxf(mx, __shfl_xor(mx, o));
                        float se = expf(v - mx);
                        #pragma unroll
                        for (int o = 1; o < 16; o <<= 1) se += __shfl_xor(se, o);
                        if (lc == 0) { wm[w][fm*16 + lr*4 + r] = mx;
                                       wsum[w][fm*16 + lr*4 + r] = se; }
                    }
                }
                __syncthreads();
                if (tid < 64) {
                    float M = wm[0][tid];
                    #pragma unroll
                    for (int i = 1; i < 8; ++i) M = fmaxf(M, wm[i][tid]);
                    float S = 0.f;
                    #pragma unroll
                    for (int i = 0; i < 8; ++i) S += wsum[i][tid] * expf(wm[i][tid] - M);
                    ms[u*64 + tid] = make_float2(M, S);
                }
            }
        } else {
            // ---- ph 7: merge 250 (m,s) partials per row, subtract lse in place ----
            for (int u = bid; u < 256; u += 256) {
                __syncthreads();
                int b = u >> 2, ch = u & 3;
                float2* red2 = (float2*)AsS;
                red2[tid] = (tid < 250) ? ms[tid*64 + b] : make_float2(-1e30f, 0.f);
                __syncthreads();
                for (int o = 256; o > 0; o >>= 1) {
                    if (tid < o) {
                        float2 a = red2[tid], c = red2[tid + o];
                        float M = fmaxf(a.x, c.x);
                        float S = a.y * expf(a.x - M) + c.y * expf(c.x - M);
                        red2[tid] = make_float2(M, S);
                    }
                    __syncthreads();
                }
                float lse = red2[0].x + logf(red2[0].y);
                float4* pr = (float4*)(logp + (size_t)b*VV) + ch*2000;
                for (int i = tid; i < 2000; i += 512) {
                    float4 v = pr[i];
                    v.x -= lse; v.y -= lse; v.z -= lse; v.w -= lse;
                    pr[i] = v;
                }
            }
        }
    }
}

// ================================================================
extern "C" void kernel_launch(void* const* d_in, const int* in_sizes, int n_in,
                              void* d_out, int out_size, void* d_ws, size_t ws_size,
                              hipStream_t stream)
{
    const int*   tokens   = (const int*)  d_in[0];
    const float* h0       = (const float*)d_in[1];
    const float* c0       = (const float*)d_in[2];
    const float* enc      = (const float*)d_in[3];
    const float* emb      = (const float*)d_in[4];
    const float* W_ih     = (const float*)d_in[5];
    const float* W_hh     = (const float*)d_in[6];
    const float* b_ih     = (const float*)d_in[7];
    const float* b_hh     = (const float*)d_in[8];
    const float* attn_W   = (const float*)d_in[9];
    const float* attn_v   = (const float*)d_in[11];
    const float* concat_W = (const float*)d_in[12];
    const float* concat_b = (const float*)d_in[13];
    const float* out_W    = (const float*)d_in[14];
    const float* out_b    = (const float*)d_in[15];

    float* out  = (float*)d_out;
    float* logp = out;                      // [64, 32000]
    float* h_n  = out + (size_t)BB*VV;      // [2, 64, 1024]
    float* c_n  = h_n + 2*BB*HH;            // [2, 64, 1024]

    // workspace (floats)
    float* ws     = (float*)d_ws;
    float* gates  = ws;                       // [8][64][4096]
    float* catP   = gates + (size_t)8*BB*4096;// [8][64][1024]
    float* h1     = catP + (size_t)8*BB*HH;   // [64][1024]
    float* h_top  = h1   + BB*HH;
    float* ctx    = h_top + BB*HH;
    float* h_c    = ctx  + BB*HH;
    float* u_e    = h_c  + BB*HH;             // [1024]
    float* scores = u_e  + HH;                // [64][128]
    float2* ms    = (float2*)(scores + BB*SRC); // [250][64]

    int plo = 0, phi = 7;
    void* args[] = { &tokens, &h0, &c0, &enc, &emb, &W_ih, &W_hh, &b_ih, &b_hh,
                     &attn_W, &attn_v, &concat_W, &concat_b, &out_W, &out_b,
                     &logp, &h_n, &c_n, &gates, &h1, &h_top, &ctx, &h_c,
                     &u_e, &scores, &ms, &catP, &plo, &phi };
    hipError_t e = hipLaunchCooperativeKernel((void*)mega, dim3(256), dim3(512),
                                              args, 0, stream);
    if (e != hipSuccess) {
        // fallback: identical math as 8 sequential plain launches
        for (int p = 0; p < 8; ++p)
            mega<<<256, 512, 0, stream>>>(tokens, h0, c0, enc, emb, W_ih, W_hh,
                                          b_ih, b_hh, attn_W, attn_v,
                                          concat_W, concat_b, out_W, out_b,
                                          logp, h_n, c_n, gates, h1, h_top, ctx, h_c,
                                          u_e, scores, ms, catP, p, p);
    }
}

// Round 10
// 106.367 us; speedup vs baseline: 3.2323x; 3.2323x over previous
//
#include <hip/hip_runtime.h>
#include <math.h>

#define BB 64
#define HH 1024
#define VV 32000
#define SRC 128
#define SLSTM 8
#define SCAT 8

typedef __attribute__((ext_vector_type(8))) __bf16 bf16x8;
typedef __attribute__((ext_vector_type(8))) unsigned short ushort8;
typedef __attribute__((ext_vector_type(4))) float f32x4;

__device__ __forceinline__ float sigmoidf_(float x){ return 1.f/(1.f+expf(-x)); }

__device__ __forceinline__ unsigned short f2bf(float f){
    union { float f; unsigned u; } v; v.f = f;
    unsigned r = v.u + 0x7FFFu + ((v.u >> 16) & 1u);   // round-to-nearest-even
    return (unsigned short)(r >> 16);
}

__device__ __forceinline__ void cvt8(const float4& x, const float4& y, unsigned short* dst){
    ushort8 s;
    s[0]=f2bf(x.x); s[1]=f2bf(x.y); s[2]=f2bf(x.z); s[3]=f2bf(x.w);
    s[4]=f2bf(y.x); s[5]=f2bf(y.y); s[6]=f2bf(y.z); s[7]=f2bf(y.w);
    *(ushort8*)dst = s;
}

// ---- 64x128 MFMA tile, 512 threads (8 waves, wave w owns 16 cols) ----
// 2-deep register prefetch (two named staging sets, template-unrolled NT so all
// indexing is static) + double-buffered LDS, ONE barrier per BK=64 tile.
// A[64,*] from two row-major sources split at k=1024 (optional row-gather tk on A0);
// B row-major [N,K] split at global-k K0. kbase must be 256-aligned.
template<int NT>
__device__ __forceinline__ void tile_mm(
    const int* tk, const float* A0, const float* A1,
    const float* B0, const float* B1, int K0, int ldb,
    int n0, int kbase,
    unsigned short* AsL, unsigned short* BsL, f32x4* acc)
{
    const int tid = threadIdx.x;
    const int am = tid >> 3, ak = (tid & 7) << 3;   // A: 64 rows x 8-float chunks
    const int bn = tid >> 2, bk = (tid & 3) << 4;   // B: 128 rows x 16-float chunks
    const int arow = tk ? tk[am] : am;
    float4 aA[2], bA[4], aB[2], bB[4];              // two staging sets (even/odd tiles)

    auto loadG = [&](int t, float4* ar, float4* br){
        int ka = kbase + (t << 6) + ak;             // BK tile never straddles 1024
        const float* Ap = (ka < 1024) ? (A0 + (size_t)arow*HH + ka)
                                      : (A1 + (size_t)am*HH + (ka - 1024));
        ar[0] = *(const float4*)(Ap);
        ar[1] = *(const float4*)(Ap + 4);
        int kg = kbase + (t << 6);
        const float* Bp; int kb;
        if (kg < K0) { Bp = B0; kb = kg; } else { Bp = B1; kb = kg - K0; }
        const float* Bq = Bp + (size_t)(n0 + bn) * ldb + kb + bk;
        #pragma unroll
        for (int i = 0; i < 4; ++i) br[i] = *(const float4*)(Bq + i*4);
    };
    auto writeL = [&](int buf, const float4* ar, const float4* br){
        cvt8(ar[0], ar[1], &AsL[buf*4608 + am*72 + ak]);
        cvt8(br[0], br[1], &BsL[buf*9216 + bn*72 + bk]);
        cvt8(br[2], br[3], &BsL[buf*9216 + bn*72 + bk + 8]);
    };

    loadG(0, aA, bA);
    if (NT > 1) loadG(1, aB, bB);                   // 2 tile-loads in flight
    writeL(0, aA, bA);
    __syncthreads();

    const int lane = tid & 63, w = tid >> 6;
    const int lr = lane >> 4, lc = lane & 15;

    #pragma unroll
    for (int t = 0; t < NT; ++t) {
        const int cur = t & 1;
        // set that held tile t is free (already in LDS): refill with tile t+2
        if (t + 2 < NT) loadG(t + 2, cur ? aB : aA, cur ? bB : bA);
        #pragma unroll
        for (int ks = 0; ks < 2; ++ks) {
            bf16x8 bF = *(const bf16x8*)&BsL[cur*9216 + (w*16 + lc)*72 + ks*32 + lr*8];
            #pragma unroll
            for (int fm = 0; fm < 4; ++fm) {
                bf16x8 aF = *(const bf16x8*)&AsL[cur*4608 + (fm*16 + lc)*72 + ks*32 + lr*8];
                acc[fm] = __builtin_amdgcn_mfma_f32_16x16x32_bf16(aF, bF, acc[fm], 0, 0, 0);
            }
        }
        if (t + 1 < NT) {
            writeL(cur ^ 1, cur ? aA : aB, cur ? bA : bB);  // tile t+1 -> other buffer
            __syncthreads();                                // single barrier per tile
        }
    }
}

// ============ split-K weight GEMM (+ fused side units), 512 threads ============
// grid = (N/128, 8 [+extra]); kChunk = 256 (4 BK tiles); raw partials to C + y*64*N.
// EXTRA==1: y==8, x<16 -> u_e = (attn_W^T v)[1024:2048]
// EXTRA==2: y in 8..11 -> fused softmax(scores)+context
template<int GATHER, int EXTRA>
__global__ __launch_bounds__(512)
void gemm_bf(const int* __restrict__ tokens,
             const float* __restrict__ A0, const float* __restrict__ A1,
             const float* __restrict__ B0, const float* __restrict__ B1,
             int K0, int ldb, int N, float* __restrict__ C,
             const float* __restrict__ xa, const float* __restrict__ xb,
             float* __restrict__ xo)
{
    __shared__ __align__(16) unsigned short As[2*4608];
    __shared__ __align__(16) unsigned short Bs[2*9216];
    const int tid = threadIdx.x;

    if (EXTRA && blockIdx.y >= 8) {
        if (EXTRA == 1) {               // u_e[k] = sum_h attn_v[h]*attn_W[h][1024+k]
            if (blockIdx.x >= 16) return;
            float4 (*red4)[16] = (float4 (*)[16])As;
            int kq = tid & 15, hp = tid >> 4;       // hp 0..31
            int k = 1024 + blockIdx.x*64 + kq*4;
            float4 s4 = {0.f,0.f,0.f,0.f};
            for (int h = hp; h < HH; h += 32) {
                float vh = xb[h];
                float4 wv = *(const float4*)&xa[(size_t)h*2048 + k];
                s4.x = fmaf(vh, wv.x, s4.x); s4.y = fmaf(vh, wv.y, s4.y);
                s4.z = fmaf(vh, wv.z, s4.z); s4.w = fmaf(vh, wv.w, s4.w);
            }
            red4[hp][kq] = s4;
            __syncthreads();
            if (tid < 16) {
                float4 t4 = {0.f,0.f,0.f,0.f};
                #pragma unroll
                for (int i = 0; i < 32; ++i) {
                    float4 rv = red4[i][tid];
                    t4.x += rv.x; t4.y += rv.y; t4.z += rv.z; t4.w += rv.w;
                }
                *(float4*)&xo[blockIdx.x*64 + tid*4] = t4;
            }
        } else {                        // smctx: softmax(scores[b,:]) + context
            int sid = (blockIdx.y - 8)*32 + blockIdx.x;   // 0..127
            int b = sid >> 1;
            int h = ((sid & 1) << 9) + tid;
            float* wl = (float*)As;
            if (tid < SRC) wl[tid] = xa[b*SRC + tid];
            __syncthreads();
            float m = -INFINITY;
            #pragma unroll 8
            for (int l = 0; l < SRC; ++l) m = fmaxf(m, wl[l]);
            float sum = 0.f;
            #pragma unroll 8
            for (int l = 0; l < SRC; ++l) sum += expf(wl[l] - m);
            float inv = 1.f / sum;
            __syncthreads();
            if (tid < SRC) wl[tid] = expf(wl[tid] - m) * inv;
            __syncthreads();
            float a = 0.f;
            #pragma unroll 4
            for (int l = 0; l < SRC; ++l)
                a = fmaf(wl[l], xb[(size_t)(l*BB + b)*HH + h], a);
            xo[b*HH + h] = a;
        }
        return;
    }

    f32x4 acc[4] = {};
    const int n0 = blockIdx.x * 128;
    tile_mm<4>(GATHER ? tokens : nullptr, A0, A1, B0, B1, K0, ldb,
               n0, blockIdx.y * 256, As, Bs, acc);
    float* Cp = C + (size_t)blockIdx.y * 64 * N;
    const int lane = tid & 63, w = tid >> 6;
    const int lr = lane >> 4, lc = lane & 15;
    const int n = n0 + w*16 + lc;
    #pragma unroll
    for (int fm = 0; fm < 4; ++fm)
        #pragma unroll
        for (int r = 0; r < 4; ++r)
            Cp[(size_t)(fm*16 + lr*4 + r)*N + n] = acc[fm][r];
}

// ====== out-projection: logits = h_c @ out_W^T + b; fused per-block row (m,s) ======
__global__ __launch_bounds__(512)
void out_gemm(const float* __restrict__ A, const float* __restrict__ W,
              const float* __restrict__ bias, float* __restrict__ logits,
              float2* __restrict__ ms)
{
    __shared__ __align__(16) unsigned short As[2*4608];
    __shared__ __align__(16) unsigned short Bs[2*9216];
    __shared__ float wm[8][64], wsum[8][64];
    const int tid = threadIdx.x;
    const int n0 = blockIdx.x * 128;

    f32x4 acc[4] = {};
    tile_mm<16>(nullptr, A, A, W, W, 1 << 30, 1024, n0, 0, As, Bs, acc);

    const int lane = tid & 63, w = tid >> 6;
    const int lr = lane >> 4, lc = lane & 15;
    const int n = n0 + w*16 + lc;
    const float bv = bias[n];
    #pragma unroll
    for (int fm = 0; fm < 4; ++fm) {
        #pragma unroll
        for (int r = 0; r < 4; ++r) {
            float v = acc[fm][r] + bv;
            logits[(size_t)(fm*16 + lr*4 + r)*VV + n] = v;
            float mx = v;
            #pragma unroll
            for (int o = 1; o < 16; o <<= 1) mx = fmaxf(mx, __shfl_xor(mx, o));
            float se = expf(v - mx);
            #pragma unroll
            for (int o = 1; o < 16; o <<= 1) se += __shfl_xor(se, o);
            if (lc == 0) { wm[w][fm*16 + lr*4 + r] = mx;
                           wsum[w][fm*16 + lr*4 + r] = se; }
        }
    }
    __syncthreads();
    if (tid < 64) {
        float M = wm[0][tid];
        #pragma unroll
        for (int i = 1; i < 8; ++i) M = fmaxf(M, wm[i][tid]);
        float S = 0.f;
        #pragma unroll
        for (int i = 0; i < 8; ++i) S += wsum[i][tid] * expf(wm[i][tid] - M);
        ms[blockIdx.x*64 + tid] = make_float2(M, S);
    }
}

// ---------------- LSTM pointwise (+ optional fused attention scores) ----------------
template<int WITH_SCORES>
__global__ __launch_bounds__(256)
void lstm_point(const float* __restrict__ gates,   // [SLSTM][64][4096]
                const float* __restrict__ bih, const float* __restrict__ bhh,
                const float* __restrict__ c0,
                float* __restrict__ hn, float* __restrict__ cn,
                float* __restrict__ hout,
                const float* __restrict__ u_e, const float* __restrict__ enc,
                float* __restrict__ scores)
{
    int bid = blockIdx.x;
    if (WITH_SCORES && bid >= 256) {
        // scores[b,l] = u_e . enc[l,b,:]  (h/bias score terms cancel in softmax)
        int g = (bid - 256)*4 + (threadIdx.x >> 6);   // 0..2047, 4 pairs each
        int lane = threadIdx.x & 63;
        #pragma unroll
        for (int q = 0; q < 4; ++q) {
            int p = g*4 + q;
            int b = p >> 7, l = p & 127;
            const float* e = enc + (size_t)(l*BB + b)*HH;
            float s = 0.f;
            #pragma unroll
            for (int t = 0; t < 16; ++t)
                s = fmaf(u_e[lane + 64*t], e[lane + 64*t], s);
            #pragma unroll
            for (int o = 32; o > 0; o >>= 1) s += __shfl_xor(s, o);
            if (lane == 0) scores[b*SRC + l] = s;
        }
        return;
    }
    int idx = bid*256 + threadIdx.x;     // 0..65535
    int b = idx >> 10, k = idx & 1023;
    const float* g = gates + b*4096;
    float ig = bih[k]        + bhh[k];
    float fg = bih[1024 + k] + bhh[1024 + k];
    float gg = bih[2048 + k] + bhh[2048 + k];
    float og = bih[3072 + k] + bhh[3072 + k];
    #pragma unroll
    for (int s = 0; s < SLSTM; ++s) {
        const float* gs = g + s*BB*4096;
        ig += gs[k];
        fg += gs[1024 + k];
        gg += gs[2048 + k];
        og += gs[3072 + k];
    }
    float c = sigmoidf_(fg)*c0[b*HH + k] + sigmoidf_(ig)*tanhf(gg);
    float h = sigmoidf_(og)*tanhf(c);
    cn[b*HH + k] = c;
    hn[b*HH + k] = h;
    hout[b*HH + k] = h;
}

// ---------------- concat reduce + bias + tanh (SCAT partials) ----------------
__global__ __launch_bounds__(256)
void reduce_tanh(const float* __restrict__ P,   // [SCAT][64][1024]
                 const float* __restrict__ bias, float* __restrict__ out)
{
    int idx = blockIdx.x*256 + threadIdx.x;     // 0..65535
    int n = idx & 1023;
    float s = bias[n];
    #pragma unroll
    for (int si = 0; si < SCAT; ++si) s += P[si*65536 + idx];
    out[idx] = tanhf(s);
}

// ------- merge 250 per-block (m,s) partials -> lse[b]; subtract in place -------
__global__ __launch_bounds__(256)
void sub_final(float* __restrict__ logp, const float2* __restrict__ ms)
{
    __shared__ float2 red[256];
    int b = blockIdx.y;
    float m = -INFINITY, s = 0.f;
    if (threadIdx.x < 250) {
        float2 p = ms[threadIdx.x*64 + b];
        m = p.x; s = p.y;
    }
    red[threadIdx.x] = make_float2(m, s);
    __syncthreads();
    for (int o = 128; o > 0; o >>= 1) {
        if (threadIdx.x < o) {
            float2 a = red[threadIdx.x], c = red[threadIdx.x + o];
            float M = fmaxf(a.x, c.x);
            float S = a.y * expf(a.x - M) + c.y * expf(c.x - M);
            red[threadIdx.x] = make_float2(M, S);
        }
        __syncthreads();
    }
    float lse = red[0].x + logf(red[0].y);
    int i = blockIdx.x*256 + threadIdx.x;       // over 8000 float4
    if (i < 8000) {
        float4* p = (float4*)(logp + (size_t)b*VV);
        float4 v = p[i];
        v.x -= lse; v.y -= lse; v.z -= lse; v.w -= lse;
        p[i] = v;
    }
}

// ================================================================
extern "C" void kernel_launch(void* const* d_in, const int* in_sizes, int n_in,
                              void* d_out, int out_size, void* d_ws, size_t ws_size,
                              hipStream_t stream)
{
    const int*   tokens   = (const int*)  d_in[0];
    const float* h0       = (const float*)d_in[1];
    const float* c0       = (const float*)d_in[2];
    const float* enc      = (const float*)d_in[3];
    const float* emb      = (const float*)d_in[4];
    const float* W_ih     = (const float*)d_in[5];
    const float* W_hh     = (const float*)d_in[6];
    const float* b_ih     = (const float*)d_in[7];
    const float* b_hh     = (const float*)d_in[8];
    const float* attn_W   = (const float*)d_in[9];
    const float* attn_v   = (const float*)d_in[11];
    const float* concat_W = (const float*)d_in[12];
    const float* concat_b = (const float*)d_in[13];
    const float* out_W    = (const float*)d_in[14];
    const float* out_b    = (const float*)d_in[15];

    float* out  = (float*)d_out;
    float* logp = out;                      // [64, 32000]
    float* h_n  = out + (size_t)BB*VV;      // [2, 64, 1024]
    float* c_n  = h_n + 2*BB*HH;            // [2, 64, 1024]

    // workspace layout (floats)
    float* ws     = (float*)d_ws;
    float* gates  = ws;                       // [SLSTM=8][64][4096] partials
    float* catP   = gates;                    // [SCAT=8][64][1024] (aliases; disjoint lifetime)
    float* h1     = gates + SLSTM*262144;     // [64][1024] layer-0 hidden
    float* h_top  = h1    + 65536;            // [64][1024] layer-1 hidden
    float* ctx    = h_top + 65536;            // [64][1024] attention context
    float* h_c    = ctx   + 65536;            // [64][1024] concat output
    float* u_e    = h_c   + 65536;            // [1024]
    float* scores = u_e   + 1024;             // [64][128]
    float2* ms    = (float2*)(scores + 8192); // [250][64] (m, s)

    // 1) LSTM L0 GEMM (A = [emb[tok] ; h0[0]] gathered inline) + u_e side-blocks
    gemm_bf<1,1><<<dim3(32, 9), 512, 0, stream>>>(
        tokens, emb, h0, W_ih, W_hh, 1024, 1024, 4096, gates,
        attn_W, attn_v, u_e);

    // 2) LSTM L0 pointwise + attention scores (independent; fused grid)
    lstm_point<1><<<768, 256, 0, stream>>>(gates, b_ih, b_hh, c0,
                                           h_n, c_n, h1, u_e, enc, scores);

    // 3) LSTM L1 GEMM (A = [h1 ; h0[1]]) + fused softmax/context side-blocks
    gemm_bf<0,2><<<dim3(32, 12), 512, 0, stream>>>(
        nullptr, h1, h0 + BB*HH,
        W_ih + (size_t)4096*1024, W_hh + (size_t)4096*1024, 1024, 1024,
        4096, gates, scores, enc, ctx);

    // 4) LSTM L1 pointwise
    lstm_point<0><<<256, 256, 0, stream>>>(gates, b_ih + 4096, b_hh + 4096, c0 + BB*HH,
                                           h_n + BB*HH, c_n + BB*HH, h_top,
                                           nullptr, nullptr, nullptr);

    // 5) concat GEMM (A = [ctx ; h_top], K=2048) -> partials
    gemm_bf<0,0><<<dim3(8, 8), 512, 0, stream>>>(
        nullptr, ctx, h_top, concat_W, nullptr, 1 << 30, 2048,
        1024, catP, nullptr, nullptr, nullptr);

    // 6) reduce + bias + tanh -> h_c
    reduce_tanh<<<256, 256, 0, stream>>>(catP, concat_b, h_c);

    // 7) out-projection: logits (+bias) direct to d_out + per-block row (m,s) partials
    out_gemm<<<250, 512, 0, stream>>>(h_c, out_W, out_b, logp, ms);

    // 8) merge partials -> lse, subtract in place
    sub_final<<<dim3(32, 64), 256, 0, stream>>>(logp, ms);
}